// Round 7
// baseline (269.082 us; speedup 1.0000x reference)
//
#include <hip/hip_runtime.h>
#include <hip/hip_bf16.h>
#include <math.h>

#define B_   128
#define Qn   30
#define Dn   200
#define En   300

typedef __attribute__((ext_vector_type(8))) short short8;
typedef __attribute__((ext_vector_type(4))) float floatx4;
typedef unsigned int u32;
typedef unsigned short u16;

typedef const __attribute__((address_space(1))) unsigned int* gas_ptr;
typedef __attribute__((address_space(3))) unsigned int* las_ptr;

static __device__ __forceinline__ void gld_lds16(const void* g, void* l) {
    __builtin_amdgcn_global_load_lds((gas_ptr)g, (las_ptr)l, 16, 0, 0);
}

static __device__ __forceinline__ u16 f2b(float x) {   // fp32 -> bf16 RNE
    union { float f; u32 u; } v; v.f = x;
    u32 r = v.u + 0x7FFFu + ((v.u >> 16) & 1u);
    return (u16)(r >> 16);
}
static __device__ __forceinline__ float bits2f(u32 u) {
    union { u32 u2; float f; } v; v.u2 = u; return v.f;
}

// ---------------------------------------------------------------------------
// prep_w: weight permute only. Wt2 per-gram layout:
//   gram g (ntap taps) base: [ks 10][j ntap][nt 8][q4 4][c16 16][k8 8] bf16
//   (inner 1024 B group == lane*16 for lane = qd4*16 + l15 -> DMA/frag friendly)
// ---------------------------------------------------------------------------
__global__ void prep_w_kernel(const float* __restrict__ w1, const float* __restrict__ w2,
                              const float* __restrict__ w3, u16* __restrict__ Wt2) {
    int p = blockIdx.x * 256 + threadIdx.x;
    if (p >= 245760) return;
    int g, ntap, o;
    if (p < 40960)       { g=0; ntap=1; o=p; }
    else if (p < 122880) { g=1; ntap=2; o=p-40960; }
    else                 { g=2; ntap=3; o=p-122880; }
    int ks = o / (ntap*4096);
    int r  = o - ks*(ntap*4096);
    int j  = r / 4096;
    int r2 = r & 4095;
    int nt = r2 >> 9;
    int r3 = r2 & 511;
    int q4 = r3 >> 7;
    int c16 = (r3 >> 3) & 15;
    int k8 = r3 & 7;
    int ch = nt*16 + c16;
    int e  = ks*32 + q4*8 + k8;
    float v = 0.f;
    if (e < En) {
        if (g == 0)      v = w1[ch*En + e];
        else if (g == 1) v = w2[(ch*En + e)*2 + j];
        else             v = w3[(ch*En + e)*3 + j];
    }
    Wt2[p] = f2b(v);
}

// ---------------------------------------------------------------------------
// Conv, fused gather: row space per b = 256 positions (0..199 d, 200..207 zero,
// 208..237 q, 238..255 zero). Double-buffered B via global_load_lds, ONE
// barrier per K-slice. Epilogue: bias+relu+bf16 -> Gs (overlaid on A region)
// -> row inverse-norms + coalesced store.
// ---------------------------------------------------------------------------
template<int NTAP>
static __device__ __forceinline__ void conv_body64(
    int tile, int gram,
    const int* __restrict__ qtok, const int* __restrict__ dtok,
    const float* __restrict__ emb, const u16* __restrict__ Wt2g,
    const float* __restrict__ bp,
    u16* __restrict__ qg, u16* __restrict__ dg,
    float* __restrict__ invnq, float* __restrict__ invnd, char* smem)
{
    char* As  = smem;                          // [66][656 B] = 43296
    char* Bs0 = smem + 43296;                  // NTAP*8192
    char* Bs1 = smem + 43296 + NTAP*8192;      // NTAP*8192
    __shared__ int toks[66];

    const int tid = threadIdx.x;
    const int wv = tid >> 6, lane = tid & 63;
    const int l15 = lane & 15, qd4 = lane >> 4;
    const int mh = wv >> 1, nh = wv & 1;

    if (tid < 66) {
        int gR = tile*64 + tid;
        int tok = -1;
        if (gR < 32768) {
            int bb = gR >> 8, pos = gR & 255;
            if (pos < Dn) tok = dtok[bb*Dn + pos];
            else if (pos >= 208 && pos < 238) tok = qtok[bb*Qn + (pos - 208)];
        }
        toks[tid] = tok;
    }
    __syncthreads();

    // issue B DMA for ks=0 -> Bs0
    {
        const char* src = (const char*)Wt2g + lane*16;
        #pragma unroll
        for (int i = 0; i < NTAP*2; ++i) {
            int chunk = wv*NTAP*2 + i;
            gld_lds16(src + chunk*1024, Bs0 + chunk*1024);
        }
    }
    // gather embeddings -> bf16 A (overlaps DMA0)
    for (int f = tid; f < 66*75; f += 256) {
        int row = f / 75, e4 = f - row*75;
        int t = toks[row];
        u16 o0=0,o1=0,o2=0,o3=0;
        if (t >= 0) {
            float4 v = *(const float4*)(emb + t*En + e4*4);
            o0=f2b(v.x); o1=f2b(v.y); o2=f2b(v.z); o3=f2b(v.w);
        }
        u16* pp = (u16*)(As + row*656 + e4*8);
        pp[0]=o0; pp[1]=o1; pp[2]=o2; pp[3]=o3;
    }
    for (int f = tid; f < 66*14; f += 256) {
        int row = f / 14, cc = f - row*14;
        *(u32*)(As + row*656 + 600 + cc*4) = 0u;
    }

    float bias[4];
    #pragma unroll
    for (int nt = 0; nt < 4; ++nt) bias[nt] = bp[nh*64 + nt*16 + l15];

    floatx4 acc[2][4];
    #pragma unroll
    for (int mt = 0; mt < 2; ++mt)
        #pragma unroll
        for (int nt = 0; nt < 4; ++nt)
            acc[mt][nt] = (floatx4){0.f,0.f,0.f,0.f};

    __syncthreads();                           // A ready + DMA0 drained

    for (int ks = 0; ks < 10; ++ks) {
        char* Bcur = (ks & 1) ? Bs1 : Bs0;
        char* Bnxt = (ks & 1) ? Bs0 : Bs1;
        if (ks < 9) {                          // prefetch ks+1 (flies during MFMAs)
            const char* src = (const char*)Wt2g + (ks+1)*NTAP*8192 + lane*16;
            #pragma unroll
            for (int i = 0; i < NTAP*2; ++i) {
                int chunk = wv*NTAP*2 + i;
                gld_lds16(src + chunk*1024, Bnxt + chunk*1024);
            }
        }
        short8 af[2][NTAP];
        #pragma unroll
        for (int mt = 0; mt < 2; ++mt)
            #pragma unroll
            for (int j = 0; j < NTAP; ++j)
                af[mt][j] = *(const short8*)(As + (mh*32 + mt*16 + l15 + j)*656 + ks*64 + qd4*16);
        #pragma unroll
        for (int j = 0; j < NTAP; ++j) {
            short8 bfj[4];
            #pragma unroll
            for (int nt = 0; nt < 4; ++nt)
                bfj[nt] = *(const short8*)(Bcur + (j*8 + nh*4 + nt)*1024 + lane*16);
            #pragma unroll
            for (int mt = 0; mt < 2; ++mt)
                #pragma unroll
                for (int nt = 0; nt < 4; ++nt)
                    acc[mt][nt] = __builtin_amdgcn_mfma_f32_16x16x32_bf16(
                        af[mt][j], bfj[nt], acc[mt][nt], 0, 0, 0);
        }
        __syncthreads();                       // B reads done + DMA(ks+1) drained
    }

    // epilogue: Gs overlaid on A region (all A reads complete)
    u16* Gs = (u16*)As;                        // [64][136]
    #pragma unroll
    for (int mt = 0; mt < 2; ++mt)
        #pragma unroll
        for (int nt = 0; nt < 4; ++nt) {
            int ch = nh*64 + nt*16 + l15;
            #pragma unroll
            for (int i = 0; i < 4; ++i) {
                int row = mh*32 + mt*16 + qd4*4 + i;
                Gs[row*136 + ch] = f2b(fmaxf(acc[mt][nt][i] + bias[nt], 0.f));
            }
        }
    __syncthreads();

    if (tid < 64) {
        const char* rp = (const char*)Gs + tid*272;
        float ssum = 0.f;
        #pragma unroll
        for (int t16 = 0; t16 < 16; ++t16) {
            uint4 u = *(const uint4*)(rp + t16*16);
            float x;
            x = bits2f(u.x << 16); ssum += x*x;  x = bits2f(u.x & 0xffff0000u); ssum += x*x;
            x = bits2f(u.y << 16); ssum += x*x;  x = bits2f(u.y & 0xffff0000u); ssum += x*x;
            x = bits2f(u.z << 16); ssum += x*x;  x = bits2f(u.z & 0xffff0000u); ssum += x*x;
            x = bits2f(u.w << 16); ssum += x*x;  x = bits2f(u.w & 0xffff0000u); ssum += x*x;
        }
        float inv = 1.f / (sqrtf(ssum) + 1e-13f);
        int gR = tile*64 + tid;
        int b = gR >> 8, pos = gR & 255;
        if (pos < 208)      invnd[(gram*B_ + b)*208 + pos] = inv;
        else if (pos < 238) invnq[(gram*B_ + b)*32 + (pos - 208)] = inv;
    }
    #pragma unroll
    for (int i = 0; i < 4; ++i) {
        int idx = tid + i*256;                 // 64 rows x 16 uint4
        int r = idx >> 4, c16 = idx & 15;
        uint4 v = *(const uint4*)((const char*)Gs + r*272 + c16*16);
        int gR = tile*64 + r;
        int b = gR >> 8, pos = gR & 255;
        if (pos < 208)      *(uint4*)(dg + ((gram*B_ + b)*208 + pos)*128 + c16*8) = v;
        else if (pos < 238) *(uint4*)(qg + ((gram*B_ + b)*32 + (pos - 208))*128 + c16*8) = v;
    }
}

// g2 (3 taps): M=32 so LDS fits 2 blocks/CU. Waves: wv = channel quarter.
static __device__ __forceinline__ void conv_body32(
    int tile,
    const int* __restrict__ qtok, const int* __restrict__ dtok,
    const float* __restrict__ emb, const u16* __restrict__ Wt2g,
    const float* __restrict__ bp,
    u16* __restrict__ qg, u16* __restrict__ dg,
    float* __restrict__ invnq, float* __restrict__ invnd, char* smem)
{
    char* As  = smem;                          // [34][656 B] = 22304
    char* Bs0 = smem + 22304;                  // 24576
    char* Bs1 = smem + 46880;                  // 24576
    __shared__ int toks[34];

    const int tid = threadIdx.x;
    const int wv = tid >> 6, lane = tid & 63;
    const int l15 = lane & 15, qd4 = lane >> 4;

    if (tid < 34) {
        int gR = tile*32 + tid;
        int tok = -1;
        if (gR < 32768) {
            int bb = gR >> 8, pos = gR & 255;
            if (pos < Dn) tok = dtok[bb*Dn + pos];
            else if (pos >= 208 && pos < 238) tok = qtok[bb*Qn + (pos - 208)];
        }
        toks[tid] = tok;
    }
    __syncthreads();

    {
        const char* src = (const char*)Wt2g + lane*16;
        #pragma unroll
        for (int i = 0; i < 6; ++i) {
            int chunk = wv*6 + i;
            gld_lds16(src + chunk*1024, Bs0 + chunk*1024);
        }
    }
    for (int f = tid; f < 34*75; f += 256) {
        int row = f / 75, e4 = f - row*75;
        int t = toks[row];
        u16 o0=0,o1=0,o2=0,o3=0;
        if (t >= 0) {
            float4 v = *(const float4*)(emb + t*En + e4*4);
            o0=f2b(v.x); o1=f2b(v.y); o2=f2b(v.z); o3=f2b(v.w);
        }
        u16* pp = (u16*)(As + row*656 + e4*8);
        pp[0]=o0; pp[1]=o1; pp[2]=o2; pp[3]=o3;
    }
    for (int f = tid; f < 34*14; f += 256) {
        int row = f / 14, cc = f - row*14;
        *(u32*)(As + row*656 + 600 + cc*4) = 0u;
    }

    float bias[2];
    #pragma unroll
    for (int nt = 0; nt < 2; ++nt) bias[nt] = bp[wv*32 + nt*16 + l15];

    floatx4 acc[2][2];
    #pragma unroll
    for (int mt = 0; mt < 2; ++mt)
        #pragma unroll
        for (int nt = 0; nt < 2; ++nt)
            acc[mt][nt] = (floatx4){0.f,0.f,0.f,0.f};

    __syncthreads();

    for (int ks = 0; ks < 10; ++ks) {
        char* Bcur = (ks & 1) ? Bs1 : Bs0;
        char* Bnxt = (ks & 1) ? Bs0 : Bs1;
        if (ks < 9) {
            const char* src = (const char*)Wt2g + (ks+1)*24576 + lane*16;
            #pragma unroll
            for (int i = 0; i < 6; ++i) {
                int chunk = wv*6 + i;
                gld_lds16(src + chunk*1024, Bnxt + chunk*1024);
            }
        }
        short8 af[2][3];
        #pragma unroll
        for (int mt = 0; mt < 2; ++mt)
            #pragma unroll
            for (int j = 0; j < 3; ++j)
                af[mt][j] = *(const short8*)(As + (mt*16 + l15 + j)*656 + ks*64 + qd4*16);
        #pragma unroll
        for (int j = 0; j < 3; ++j) {
            short8 bfj[2];
            #pragma unroll
            for (int nt = 0; nt < 2; ++nt)
                bfj[nt] = *(const short8*)(Bcur + (j*8 + wv*2 + nt)*1024 + lane*16);
            #pragma unroll
            for (int mt = 0; mt < 2; ++mt)
                #pragma unroll
                for (int nt = 0; nt < 2; ++nt)
                    acc[mt][nt] = __builtin_amdgcn_mfma_f32_16x16x32_bf16(
                        af[mt][j], bfj[nt], acc[mt][nt], 0, 0, 0);
        }
        __syncthreads();
    }

    u16* Gs = (u16*)As;                        // [32][136]
    #pragma unroll
    for (int mt = 0; mt < 2; ++mt)
        #pragma unroll
        for (int nt = 0; nt < 2; ++nt) {
            int ch = wv*32 + nt*16 + l15;
            #pragma unroll
            for (int i = 0; i < 4; ++i) {
                int row = mt*16 + qd4*4 + i;
                Gs[row*136 + ch] = f2b(fmaxf(acc[mt][nt][i] + bias[nt], 0.f));
            }
        }
    __syncthreads();

    if (tid < 32) {
        const char* rp = (const char*)Gs + tid*272;
        float ssum = 0.f;
        #pragma unroll
        for (int t16 = 0; t16 < 16; ++t16) {
            uint4 u = *(const uint4*)(rp + t16*16);
            float x;
            x = bits2f(u.x << 16); ssum += x*x;  x = bits2f(u.x & 0xffff0000u); ssum += x*x;
            x = bits2f(u.y << 16); ssum += x*x;  x = bits2f(u.y & 0xffff0000u); ssum += x*x;
            x = bits2f(u.z << 16); ssum += x*x;  x = bits2f(u.z & 0xffff0000u); ssum += x*x;
            x = bits2f(u.w << 16); ssum += x*x;  x = bits2f(u.w & 0xffff0000u); ssum += x*x;
        }
        float inv = 1.f / (sqrtf(ssum) + 1e-13f);
        int gR = tile*32 + tid;
        int b = gR >> 8, pos = gR & 255;
        if (pos < 208)      invnd[(2*B_ + b)*208 + pos] = inv;
        else if (pos < 238) invnq[(2*B_ + b)*32 + (pos - 208)] = inv;
    }
    #pragma unroll
    for (int i = 0; i < 2; ++i) {
        int idx = tid + i*256;                 // 32 rows x 16 uint4
        int r = idx >> 4, c16 = idx & 15;
        uint4 v = *(const uint4*)((const char*)Gs + r*272 + c16*16);
        int gR = tile*32 + r;
        int b = gR >> 8, pos = gR & 255;
        if (pos < 208)      *(uint4*)(dg + ((2*B_ + b)*208 + pos)*128 + c16*8) = v;
        else if (pos < 238) *(uint4*)(qg + ((2*B_ + b)*32 + (pos - 208))*128 + c16*8) = v;
    }
}

__global__ __launch_bounds__(256, 2) void conv_kernel(
    const int* __restrict__ qtok, const int* __restrict__ dtok,
    const float* __restrict__ emb, const u16* __restrict__ Wt2,
    const float* __restrict__ b1, const float* __restrict__ b2, const float* __restrict__ b3,
    u16* __restrict__ qg, u16* __restrict__ dg,
    float* __restrict__ invnq, float* __restrict__ invnd)
{
    extern __shared__ char smem[];
    int bx = blockIdx.x;
    if (bx < 512)
        conv_body64<1>(bx, 0, qtok, dtok, emb, Wt2,          b1, qg, dg, invnq, invnd, smem);
    else if (bx < 1024)
        conv_body64<2>(bx-512, 1, qtok, dtok, emb, Wt2+40960, b2, qg, dg, invnq, invnd, smem);
    else
        conv_body32(bx-1024, qtok, dtok, emb, Wt2+122880,     b3, qg, dg, invnq, invnd, smem);
}

// ---------------------------------------------------------------------------
// Pool: block per (dj, b); grid (3, 128) -> 384 blocks, all co-resident.
// One d-tile staging serves all 3 qi. RBF exp-chain (3 transcendentals).
// Fused log+mask+q-reduce -> feats.
// ---------------------------------------------------------------------------
__global__ __launch_bounds__(256, 2) void pool_kernel(
    const u16* __restrict__ qg, const u16* __restrict__ dg,
    const float* __restrict__ invnq, const float* __restrict__ invnd,
    const int* __restrict__ qtok, const int* __restrict__ dtok,
    float* __restrict__ feats)
{
    __shared__ __align__(16) u16 dsb[208*136];     // 56576 B
    __shared__ float pk[96*12];                    // 4608 B
    __shared__ float invqA[96];
    __shared__ float qmA[96];
    __shared__ __align__(16) float invd[208];

    const int tid = threadIdx.x;
    const int b = blockIdx.y, dj = blockIdx.x;
    const int wv = tid >> 6, lane = tid & 63;
    const int l15 = lane & 15, qd4 = lane >> 4;

    for (int idx = tid; idx < 208*16; idx += 256) {
        int r = idx >> 4, ch = idx & 15;
        uint4 v = make_uint4(0u,0u,0u,0u);
        if (r < Dn) v = *(const uint4*)(dg + ((dj*B_ + b)*208 + r)*128 + ch*8);
        *(uint4*)((char*)dsb + r*272 + ch*16) = v;
    }
    if (tid < 208) {
        float v = invnd[(dj*B_ + b)*208 + tid];
        bool ok = (tid < Dn) && (dtok[b*Dn + tid] > 0);
        invd[tid] = ok ? v : (-fabsf(v) - 1.0f);   // strictly negative if masked
    }
    if (tid < 96) {
        int qi = tid >> 5, qr = tid & 31;
        float v = invnq[(qi*B_ + b)*32 + qr];
        bool ok = (qr < Qn) && (qtok[b*Qn + qr] > 0);
        invqA[tid] = ok ? v : 0.f;
        qmA[tid] = ok ? 1.f : 0.f;
    }
    for (int i = tid; i < 96*12; i += 256) pk[i] = 0.f;
    __syncthreads();

    // chain constants C_k = exp(10*(mu_k + mu_{k+1})), mu: 0.9,0.7,...,-0.9
    const float CkR[9] = {8886110.5f, 162754.79f, 2980.958f, 54.598150f, 1.0f,
                          0.018315639f, 3.3546263e-4f, 6.1442124e-6f, 1.1253517e-7f};

    for (int qi = 0; qi < 3; ++qi) {
        short8 qf[2][4];
        float vq[2];
        #pragma unroll
        for (int qt = 0; qt < 2; ++qt) {
            vq[qt] = invqA[qi*32 + qt*16 + l15];
            #pragma unroll
            for (int ks = 0; ks < 4; ++ks)
                qf[qt][ks] = *(const short8*)(qg + ((qi*B_ + b)*32 + qt*16 + l15)*128 + ks*32 + qd4*8);
        }
        float pkl[2][11];
        #pragma unroll
        for (int qt = 0; qt < 2; ++qt)
            #pragma unroll
            for (int k = 0; k < 11; ++k) pkl[qt][k] = 0.f;

        for (int t = wv; t < 13; t += 4) {
            short8 af[4];
            #pragma unroll
            for (int ks = 0; ks < 4; ++ks)
                af[ks] = *(const short8*)((const char*)dsb + (t*16 + l15)*272 + ks*64 + qd4*16);
            floatx4 acc[2];
            acc[0] = (floatx4){0.f,0.f,0.f,0.f};
            acc[1] = (floatx4){0.f,0.f,0.f,0.f};
            #pragma unroll
            for (int ks = 0; ks < 4; ++ks)
                #pragma unroll
                for (int qt = 0; qt < 2; ++qt)
                    acc[qt] = __builtin_amdgcn_mfma_f32_16x16x32_bf16(af[ks], qf[qt][ks], acc[qt], 0, 0, 0);
            floatx4 iv4 = *(const floatx4*)(invd + t*16 + qd4*4);
            #pragma unroll
            for (int qt = 0; qt < 2; ++qt)
                #pragma unroll
                for (int i = 0; i < 4; ++i) {
                    float cs = acc[qt][i] * vq[qt] * iv4[i];
                    cs = (cs > 0.f) ? cs : 2.0f;   // masked/zero -> all kernels ~0
                    float t0 = cs - 1.0f;
                    float u  = cs - 0.9f;
                    float s0 = __expf(-500000.f * t0 * t0);
                    float e  = __expf(-50.f * u * u);
                    float rr = __expf(-20.f * cs);
                    pkl[qt][0] += s0;
                    pkl[qt][1] += e;
                    #pragma unroll
                    for (int kk = 0; kk < 9; ++kk) {
                        e = e * rr * CkR[kk];
                        pkl[qt][2 + kk] += e;
                    }
                }
        }
        #pragma unroll
        for (int qt = 0; qt < 2; ++qt)
            #pragma unroll
            for (int k = 0; k < 11; ++k) {
                float v = pkl[qt][k];
                v += __shfl_xor(v, 16);
                v += __shfl_xor(v, 32);
                if (qd4 == 0) atomicAdd(&pk[(qi*32 + qt*16 + l15)*12 + k], v);
            }
    }
    __syncthreads();

    if (tid < 33) {
        int qi = tid / 11, k = tid - qi*11;
        float s = 0.f;
        for (int q = 0; q < Qn; ++q)
            s += qmA[qi*32 + q] * 0.01f * __logf(fmaxf(pk[(qi*32 + q)*12 + k], 1e-10f));
        feats[(b*9 + qi*3 + dj)*11 + k] = s;
    }
}

// ---------------------------------------------------------------------------
__global__ void final_kernel(const float* __restrict__ feats,
                             const float* __restrict__ dw,
                             float* __restrict__ out) {
    int b = threadIdx.x;
    if (b < B_) {
        float s = 0.f;
        for (int f = 0; f < 99; ++f) s += feats[b*99 + f] * dw[f];
        out[b] = s;
    }
}

extern "C" void kernel_launch(void* const* d_in, const int* in_sizes, int n_in,
                              void* d_out, int out_size, void* d_ws, size_t ws_size,
                              hipStream_t stream) {
    const int*   qtok = (const int*)d_in[0];
    const int*   dtok = (const int*)d_in[1];
    const float* emb  = (const float*)d_in[2];
    const float* w1   = (const float*)d_in[3];
    const float* w2   = (const float*)d_in[4];
    const float* w3   = (const float*)d_in[5];
    const float* b1   = (const float*)d_in[6];
    const float* b2   = (const float*)d_in[7];
    const float* b3   = (const float*)d_in[8];
    const float* dw   = (const float*)d_in[9];
    float* out = (float*)d_out;

    char* w = (char*)d_ws;
    u16*   Wt2   = (u16*)w;                      // 491,520 B
    u16*   qg    = (u16*)(w + 491520);           // 3*128*32*128*2  = 3,145,728
    u16*   dgm   = (u16*)(w + 3637248);          // 3*128*208*128*2 = 20,447,232
    float* invq_ = (float*)(w + 24084480);       // 49,152
    float* invd_ = (float*)(w + 24133632);       // 319,488
    float* feats = (float*)(w + 24453120);       // 50,688 -> total 24,503,808

    prep_w_kernel<<<960, 256, 0, stream>>>(w1, w2, w3, Wt2);

    const int conv_lds = 76064;                  // g1 worst case; 2 blocks/CU for all grams
    hipFuncSetAttribute(reinterpret_cast<const void*>(conv_kernel),
                        hipFuncAttributeMaxDynamicSharedMemorySize, conv_lds);
    conv_kernel<<<dim3(2048), 256, conv_lds, stream>>>(
        qtok, dtok, emb, Wt2, b1, b2, b3, qg, dgm, invq_, invd_);

    pool_kernel<<<dim3(3, B_), 256, 0, stream>>>(qg, dgm, invq_, invd_, qtok, dtok, feats);

    final_kernel<<<1, 128, 0, stream>>>(feats, dw, out);
}

// Round 8
// 184.306 us; speedup vs baseline: 1.4600x; 1.4600x over previous
//
#include <hip/hip_runtime.h>
#include <hip/hip_bf16.h>
#include <math.h>

#define B_   128
#define Qn   30
#define Dn   200
#define En   300

typedef __attribute__((ext_vector_type(8))) short short8;
typedef __attribute__((ext_vector_type(4))) float floatx4;
typedef unsigned int u32;
typedef unsigned short u16;

typedef const __attribute__((address_space(1))) unsigned int* gas_ptr;
typedef __attribute__((address_space(3))) unsigned int* las_ptr;

static __device__ __forceinline__ void gld_lds16(const void* g, void* l) {
    __builtin_amdgcn_global_load_lds((gas_ptr)g, (las_ptr)l, 16, 0, 0);
}

static __device__ __forceinline__ u16 f2b(float x) {   // fp32 -> bf16 RNE
    union { float f; u32 u; } v; v.f = x;
    u32 r = v.u + 0x7FFFu + ((v.u >> 16) & 1u);
    return (u16)(r >> 16);
}
static __device__ __forceinline__ float bits2f(u32 u) {
    union { u32 u2; float f; } v; v.u2 = u; return v.f;
}

// ---------------------------------------------------------------------------
// prep_gather: fused (a) token gather -> bf16 A [128 b][256 rows][320 K]
// (+2 zero rows at 32768/32769), rows per b: 0..199 d, 200..207 zero,
// 208..237 q, 238..255 zero; (b) weight permute -> Wt2 per-gram layout
// [ks 10][j ntap][nt 8][q4 4][c16 16][k8 8] bf16 (1024 B group == lane*16).
// grid (24, 128): x<16 gather; x>=16 permute. Gather runs ONCE, coalesced
// writes — keeps scattered emb reads off the conv critical path (R7 lesson).
// ---------------------------------------------------------------------------
__global__ void prep_gather_kernel(
    const int* __restrict__ qtok, const int* __restrict__ dtok,
    const float* __restrict__ emb,
    const float* __restrict__ w1, const float* __restrict__ w2, const float* __restrict__ w3,
    u16* __restrict__ Ag, u16* __restrict__ Wt2)
{
    const int tid = threadIdx.x;
    if (blockIdx.x < 16) {
        const int b = blockIdx.y, c = blockIdx.x;
        __shared__ int toks[16];
        if (tid < 16) {
            int pos = c*16 + tid;
            int tok = -1;
            if (pos < Dn) tok = dtok[b*Dn + pos];
            else if (pos >= 208 && pos < 238) tok = qtok[b*Qn + (pos - 208)];
            toks[tid] = tok;
        }
        __syncthreads();
        #pragma unroll
        for (int i = 0; i < 5; ++i) {
            int f = tid + i*256;                     // < 1280 = 16 rows * 80 col4
            int r = f / 80, c4 = f - r*80;
            int t = toks[r];
            u16 o0=0,o1=0,o2=0,o3=0;
            if (t >= 0 && c4 < 75) {
                float4 v = *(const float4*)(emb + t*En + c4*4);
                o0=f2b(v.x); o1=f2b(v.y); o2=f2b(v.z); o3=f2b(v.w);
            }
            u16* p = Ag + ((b*256 + c*16 + r)*320 + c4*4);
            p[0]=o0; p[1]=o1; p[2]=o2; p[3]=o3;
        }
        if (b == 127 && c == 15 && tid < 160) {      // 2 zero pad rows
            u16* p = Ag + (32768*320) + tid*4;
            p[0]=0; p[1]=0; p[2]=0; p[3]=0;
        }
    } else {
        int p = ((blockIdx.x - 16)*128 + blockIdx.y)*256 + tid;
        if (p >= 245760) return;
        int g, ntap, o;
        if (p < 40960)       { g=0; ntap=1; o=p; }
        else if (p < 122880) { g=1; ntap=2; o=p-40960; }
        else                 { g=2; ntap=3; o=p-122880; }
        int ks = o / (ntap*4096);
        int r  = o - ks*(ntap*4096);
        int j  = r / 4096;
        int r2 = r & 4095;
        int nt = r2 >> 9;
        int r3 = r2 & 511;
        int q4 = r3 >> 7;
        int c16 = (r3 >> 3) & 15;
        int k8 = r3 & 7;
        int ch = nt*16 + c16;
        int e  = ks*32 + q4*8 + k8;
        float v = 0.f;
        if (e < En) {
            if (g == 0)      v = w1[ch*En + e];
            else if (g == 1) v = w2[(ch*En + e)*2 + j];
            else             v = w3[(ch*En + e)*3 + j];
        }
        Wt2[p] = f2b(v);
    }
}

// ---------------------------------------------------------------------------
// Conv GEMM reading pre-gathered Ag (coalesced). Double-buffered B via
// global_load_lds, ONE barrier per K-slice (prefetch issued before MFMAs so
// its flight overlaps compute; barrier vmcnt(0) drain lands after ~full
// compute-slice). Epilogue: bias+relu+bf16 -> Gs (overlay on A region) ->
// row inverse-norms + coalesced store.
// ---------------------------------------------------------------------------
template<int NTAP>
static __device__ __forceinline__ void conv_body64(
    int tile, int gram,
    const u16* __restrict__ Ag, const u16* __restrict__ Wt2g,
    const float* __restrict__ bp,
    u16* __restrict__ qg, u16* __restrict__ dg,
    float* __restrict__ invnq, float* __restrict__ invnd, char* smem)
{
    char* As  = smem;                          // [66][656 B] = 43296
    char* Bs0 = smem + 43296;                  // NTAP*8192
    char* Bs1 = smem + 43296 + NTAP*8192;      // NTAP*8192

    const int tid = threadIdx.x;
    const int wv = tid >> 6, lane = tid & 63;
    const int l15 = lane & 15, qd4 = lane >> 4;
    const int mh = wv >> 1, nh = wv & 1;

    // issue B DMA for ks=0 -> Bs0 (no dependencies)
    {
        const char* src = (const char*)Wt2g + lane*16;
        #pragma unroll
        for (int i = 0; i < NTAP*2; ++i) {
            int chunk = wv*NTAP*2 + i;
            gld_lds16(src + chunk*1024, Bs0 + chunk*1024);
        }
    }
    // stage A: 66 rows x 640 B, fully coalesced (overlaps DMA0)
    {
        const char* base = (const char*)Ag + (size_t)tile*64*640;
        #pragma unroll
        for (int i = 0; i < 11; ++i) {
            int idx = tid + i*256;
            if (idx < 2640) {
                int r = idx / 40, c = idx - r*40;
                uint4 v = *(const uint4*)(base + r*640 + c*16);
                *(uint4*)(As + r*656 + c*16) = v;
            }
        }
    }

    float bias[4];
    #pragma unroll
    for (int nt = 0; nt < 4; ++nt) bias[nt] = bp[nh*64 + nt*16 + l15];

    floatx4 acc[2][4];
    #pragma unroll
    for (int mt = 0; mt < 2; ++mt)
        #pragma unroll
        for (int nt = 0; nt < 4; ++nt)
            acc[mt][nt] = (floatx4){0.f,0.f,0.f,0.f};

    __syncthreads();                           // A ready + DMA0 drained

    for (int ks = 0; ks < 10; ++ks) {
        char* Bcur = (ks & 1) ? Bs1 : Bs0;
        char* Bnxt = (ks & 1) ? Bs0 : Bs1;
        if (ks < 9) {                          // prefetch ks+1 (flies during MFMAs)
            const char* src = (const char*)Wt2g + (ks+1)*NTAP*8192 + lane*16;
            #pragma unroll
            for (int i = 0; i < NTAP*2; ++i) {
                int chunk = wv*NTAP*2 + i;
                gld_lds16(src + chunk*1024, Bnxt + chunk*1024);
            }
        }
        short8 af[2][NTAP];
        #pragma unroll
        for (int mt = 0; mt < 2; ++mt)
            #pragma unroll
            for (int j = 0; j < NTAP; ++j)
                af[mt][j] = *(const short8*)(As + (mh*32 + mt*16 + l15 + j)*656 + ks*64 + qd4*16);
        #pragma unroll
        for (int j = 0; j < NTAP; ++j) {
            short8 bfj[4];
            #pragma unroll
            for (int nt = 0; nt < 4; ++nt)
                bfj[nt] = *(const short8*)(Bcur + (j*8 + nh*4 + nt)*1024 + lane*16);
            #pragma unroll
            for (int mt = 0; mt < 2; ++mt)
                #pragma unroll
                for (int nt = 0; nt < 4; ++nt)
                    acc[mt][nt] = __builtin_amdgcn_mfma_f32_16x16x32_bf16(
                        af[mt][j], bfj[nt], acc[mt][nt], 0, 0, 0);
        }
        __syncthreads();                       // B reads done + DMA(ks+1) drained
    }

    u16* Gs = (u16*)As;                        // [64][136]
    #pragma unroll
    for (int mt = 0; mt < 2; ++mt)
        #pragma unroll
        for (int nt = 0; nt < 4; ++nt) {
            int ch = nh*64 + nt*16 + l15;
            #pragma unroll
            for (int i = 0; i < 4; ++i) {
                int row = mh*32 + mt*16 + qd4*4 + i;
                Gs[row*136 + ch] = f2b(fmaxf(acc[mt][nt][i] + bias[nt], 0.f));
            }
        }
    __syncthreads();

    if (tid < 64) {
        const char* rp = (const char*)Gs + tid*272;
        float ssum = 0.f;
        #pragma unroll
        for (int t16 = 0; t16 < 16; ++t16) {
            uint4 u = *(const uint4*)(rp + t16*16);
            float x;
            x = bits2f(u.x << 16); ssum += x*x;  x = bits2f(u.x & 0xffff0000u); ssum += x*x;
            x = bits2f(u.y << 16); ssum += x*x;  x = bits2f(u.y & 0xffff0000u); ssum += x*x;
            x = bits2f(u.z << 16); ssum += x*x;  x = bits2f(u.z & 0xffff0000u); ssum += x*x;
            x = bits2f(u.w << 16); ssum += x*x;  x = bits2f(u.w & 0xffff0000u); ssum += x*x;
        }
        float inv = 1.f / (sqrtf(ssum) + 1e-13f);
        int gR = tile*64 + tid;
        int b = gR >> 8, pos = gR & 255;
        if (pos < 208)      invnd[(gram*B_ + b)*208 + pos] = inv;
        else if (pos < 238) invnq[(gram*B_ + b)*32 + (pos - 208)] = inv;
    }
    #pragma unroll
    for (int i = 0; i < 4; ++i) {
        int idx = tid + i*256;                 // 64 rows x 16 uint4
        int r = idx >> 4, c16 = idx & 15;
        uint4 v = *(const uint4*)((const char*)Gs + r*272 + c16*16);
        int gR = tile*64 + r;
        int b = gR >> 8, pos = gR & 255;
        if (pos < 208)      *(uint4*)(dg + ((gram*B_ + b)*208 + pos)*128 + c16*8) = v;
        else if (pos < 238) *(uint4*)(qg + ((gram*B_ + b)*32 + (pos - 208))*128 + c16*8) = v;
    }
}

// g2 (3 taps): M=32 so double-buffered LDS keeps 2 blocks/CU.
static __device__ __forceinline__ void conv_body32(
    int tile,
    const u16* __restrict__ Ag, const u16* __restrict__ Wt2g,
    const float* __restrict__ bp,
    u16* __restrict__ qg, u16* __restrict__ dg,
    float* __restrict__ invnq, float* __restrict__ invnd, char* smem)
{
    char* As  = smem;                          // [34][656 B] = 22304
    char* Bs0 = smem + 22304;                  // 24576
    char* Bs1 = smem + 46880;                  // 24576

    const int tid = threadIdx.x;
    const int wv = tid >> 6, lane = tid & 63;
    const int l15 = lane & 15, qd4 = lane >> 4;

    {
        const char* src = (const char*)Wt2g + lane*16;
        #pragma unroll
        for (int i = 0; i < 6; ++i) {
            int chunk = wv*6 + i;
            gld_lds16(src + chunk*1024, Bs0 + chunk*1024);
        }
    }
    {
        const char* base = (const char*)Ag + (size_t)tile*32*640;
        #pragma unroll
        for (int i = 0; i < 6; ++i) {
            int idx = tid + i*256;
            if (idx < 1360) {                  // 34 rows x 40 uint4
                int r = idx / 40, c = idx - r*40;
                uint4 v = *(const uint4*)(base + r*640 + c*16);
                *(uint4*)(As + r*656 + c*16) = v;
            }
        }
    }

    float bias[2];
    #pragma unroll
    for (int nt = 0; nt < 2; ++nt) bias[nt] = bp[wv*32 + nt*16 + l15];

    floatx4 acc[2][2];
    #pragma unroll
    for (int mt = 0; mt < 2; ++mt)
        #pragma unroll
        for (int nt = 0; nt < 2; ++nt)
            acc[mt][nt] = (floatx4){0.f,0.f,0.f,0.f};

    __syncthreads();

    for (int ks = 0; ks < 10; ++ks) {
        char* Bcur = (ks & 1) ? Bs1 : Bs0;
        char* Bnxt = (ks & 1) ? Bs0 : Bs1;
        if (ks < 9) {
            const char* src = (const char*)Wt2g + (ks+1)*24576 + lane*16;
            #pragma unroll
            for (int i = 0; i < 6; ++i) {
                int chunk = wv*6 + i;
                gld_lds16(src + chunk*1024, Bnxt + chunk*1024);
            }
        }
        short8 af[2][3];
        #pragma unroll
        for (int mt = 0; mt < 2; ++mt)
            #pragma unroll
            for (int j = 0; j < 3; ++j)
                af[mt][j] = *(const short8*)(As + (mt*16 + l15 + j)*656 + ks*64 + qd4*16);
        #pragma unroll
        for (int j = 0; j < 3; ++j) {
            short8 bfj[2];
            #pragma unroll
            for (int nt = 0; nt < 2; ++nt)
                bfj[nt] = *(const short8*)(Bcur + (j*8 + wv*2 + nt)*1024 + lane*16);
            #pragma unroll
            for (int mt = 0; mt < 2; ++mt)
                #pragma unroll
                for (int nt = 0; nt < 2; ++nt)
                    acc[mt][nt] = __builtin_amdgcn_mfma_f32_16x16x32_bf16(
                        af[mt][j], bfj[nt], acc[mt][nt], 0, 0, 0);
        }
        __syncthreads();
    }

    u16* Gs = (u16*)As;                        // [32][136]
    #pragma unroll
    for (int mt = 0; mt < 2; ++mt)
        #pragma unroll
        for (int nt = 0; nt < 2; ++nt) {
            int ch = wv*32 + nt*16 + l15;
            #pragma unroll
            for (int i = 0; i < 4; ++i) {
                int row = mt*16 + qd4*4 + i;
                Gs[row*136 + ch] = f2b(fmaxf(acc[mt][nt][i] + bias[nt], 0.f));
            }
        }
    __syncthreads();

    if (tid < 32) {
        const char* rp = (const char*)Gs + tid*272;
        float ssum = 0.f;
        #pragma unroll
        for (int t16 = 0; t16 < 16; ++t16) {
            uint4 u = *(const uint4*)(rp + t16*16);
            float x;
            x = bits2f(u.x << 16); ssum += x*x;  x = bits2f(u.x & 0xffff0000u); ssum += x*x;
            x = bits2f(u.y << 16); ssum += x*x;  x = bits2f(u.y & 0xffff0000u); ssum += x*x;
            x = bits2f(u.z << 16); ssum += x*x;  x = bits2f(u.z & 0xffff0000u); ssum += x*x;
            x = bits2f(u.w << 16); ssum += x*x;  x = bits2f(u.w & 0xffff0000u); ssum += x*x;
        }
        float inv = 1.f / (sqrtf(ssum) + 1e-13f);
        int gR = tile*32 + tid;
        int b = gR >> 8, pos = gR & 255;
        if (pos < 208)      invnd[(2*B_ + b)*208 + pos] = inv;
        else if (pos < 238) invnq[(2*B_ + b)*32 + (pos - 208)] = inv;
    }
    #pragma unroll
    for (int i = 0; i < 2; ++i) {
        int idx = tid + i*256;                 // 32 rows x 16 uint4
        int r = idx >> 4, c16 = idx & 15;
        uint4 v = *(const uint4*)((const char*)Gs + r*272 + c16*16);
        int gR = tile*32 + r;
        int b = gR >> 8, pos = gR & 255;
        if (pos < 208)      *(uint4*)(dg + ((2*B_ + b)*208 + pos)*128 + c16*8) = v;
        else if (pos < 238) *(uint4*)(qg + ((2*B_ + b)*32 + (pos - 208))*128 + c16*8) = v;
    }
}

__global__ __launch_bounds__(256, 2) void conv_kernel(
    const u16* __restrict__ Ag, const u16* __restrict__ Wt2,
    const float* __restrict__ b1, const float* __restrict__ b2, const float* __restrict__ b3,
    u16* __restrict__ qg, u16* __restrict__ dg,
    float* __restrict__ invnq, float* __restrict__ invnd)
{
    extern __shared__ char smem[];
    int bx = blockIdx.x;
    if (bx < 512)
        conv_body64<1>(bx,      0, Ag, Wt2,        b1, qg, dg, invnq, invnd, smem);
    else if (bx < 1024)
        conv_body64<2>(bx-512,  1, Ag, Wt2+40960,  b2, qg, dg, invnq, invnd, smem);
    else
        conv_body32(bx-1024,       Ag, Wt2+122880, b3, qg, dg, invnq, invnd, smem);
}

// ---------------------------------------------------------------------------
// Pool: block per (dj, b); grid (3, 128) -> 384 blocks, all co-resident.
// One d-tile staging serves all 3 qi. RBF exp-chain (3 transcendentals).
// Fused log+mask+q-reduce -> feats.
// ---------------------------------------------------------------------------
__global__ __launch_bounds__(256, 2) void pool_kernel(
    const u16* __restrict__ qg, const u16* __restrict__ dg,
    const float* __restrict__ invnq, const float* __restrict__ invnd,
    const int* __restrict__ qtok, const int* __restrict__ dtok,
    float* __restrict__ feats)
{
    __shared__ __align__(16) u16 dsb[208*136];     // 56576 B
    __shared__ float pk[96*12];                    // 4608 B
    __shared__ float invqA[96];
    __shared__ float qmA[96];
    __shared__ __align__(16) float invd[208];

    const int tid = threadIdx.x;
    const int b = blockIdx.y, dj = blockIdx.x;
    const int wv = tid >> 6, lane = tid & 63;
    const int l15 = lane & 15, qd4 = lane >> 4;

    for (int idx = tid; idx < 208*16; idx += 256) {
        int r = idx >> 4, ch = idx & 15;
        uint4 v = make_uint4(0u,0u,0u,0u);
        if (r < Dn) v = *(const uint4*)(dg + ((dj*B_ + b)*208 + r)*128 + ch*8);
        *(uint4*)((char*)dsb + r*272 + ch*16) = v;
    }
    if (tid < 208) {
        float v = invnd[(dj*B_ + b)*208 + tid];
        bool ok = (tid < Dn) && (dtok[b*Dn + tid] > 0);
        invd[tid] = ok ? v : (-fabsf(v) - 1.0f);   // strictly negative if masked
    }
    if (tid < 96) {
        int qi = tid >> 5, qr = tid & 31;
        float v = invnq[(qi*B_ + b)*32 + qr];
        bool ok = (qr < Qn) && (qtok[b*Qn + qr] > 0);
        invqA[tid] = ok ? v : 0.f;
        qmA[tid] = ok ? 1.f : 0.f;
    }
    for (int i = tid; i < 96*12; i += 256) pk[i] = 0.f;
    __syncthreads();

    // chain constants C_k = exp(10*(mu_k + mu_{k+1})), mu: 0.9,0.7,...,-0.9
    const float CkR[9] = {8886110.5f, 162754.79f, 2980.958f, 54.598150f, 1.0f,
                          0.018315639f, 3.3546263e-4f, 6.1442124e-6f, 1.1253517e-7f};

    for (int qi = 0; qi < 3; ++qi) {
        short8 qf[2][4];
        float vq[2];
        #pragma unroll
        for (int qt = 0; qt < 2; ++qt) {
            vq[qt] = invqA[qi*32 + qt*16 + l15];
            #pragma unroll
            for (int ks = 0; ks < 4; ++ks)
                qf[qt][ks] = *(const short8*)(qg + ((qi*B_ + b)*32 + qt*16 + l15)*128 + ks*32 + qd4*8);
        }
        float pkl[2][11];
        #pragma unroll
        for (int qt = 0; qt < 2; ++qt)
            #pragma unroll
            for (int k = 0; k < 11; ++k) pkl[qt][k] = 0.f;

        for (int t = wv; t < 13; t += 4) {
            short8 af[4];
            #pragma unroll
            for (int ks = 0; ks < 4; ++ks)
                af[ks] = *(const short8*)((const char*)dsb + (t*16 + l15)*272 + ks*64 + qd4*16);
            floatx4 acc[2];
            acc[0] = (floatx4){0.f,0.f,0.f,0.f};
            acc[1] = (floatx4){0.f,0.f,0.f,0.f};
            #pragma unroll
            for (int ks = 0; ks < 4; ++ks)
                #pragma unroll
                for (int qt = 0; qt < 2; ++qt)
                    acc[qt] = __builtin_amdgcn_mfma_f32_16x16x32_bf16(af[ks], qf[qt][ks], acc[qt], 0, 0, 0);
            floatx4 iv4 = *(const floatx4*)(invd + t*16 + qd4*4);
            #pragma unroll
            for (int qt = 0; qt < 2; ++qt)
                #pragma unroll
                for (int i = 0; i < 4; ++i) {
                    float cs = acc[qt][i] * vq[qt] * iv4[i];
                    cs = (cs > 0.f) ? cs : 2.0f;   // masked/zero -> all kernels ~0
                    float t0 = cs - 1.0f;
                    float u  = cs - 0.9f;
                    float s0 = __expf(-500000.f * t0 * t0);
                    float e  = __expf(-50.f * u * u);
                    float rr = __expf(-20.f * cs);
                    pkl[qt][0] += s0;
                    pkl[qt][1] += e;
                    #pragma unroll
                    for (int kk = 0; kk < 9; ++kk) {
                        e = e * rr * CkR[kk];
                        pkl[qt][2 + kk] += e;
                    }
                }
        }
        #pragma unroll
        for (int qt = 0; qt < 2; ++qt)
            #pragma unroll
            for (int k = 0; k < 11; ++k) {
                float v = pkl[qt][k];
                v += __shfl_xor(v, 16);
                v += __shfl_xor(v, 32);
                if (qd4 == 0) atomicAdd(&pk[(qi*32 + qt*16 + l15)*12 + k], v);
            }
    }
    __syncthreads();

    if (tid < 33) {
        int qi = tid / 11, k = tid - qi*11;
        float s = 0.f;
        for (int q = 0; q < Qn; ++q)
            s += qmA[qi*32 + q] * 0.01f * __logf(fmaxf(pk[(qi*32 + q)*12 + k], 1e-10f));
        feats[(b*9 + qi*3 + dj)*11 + k] = s;
    }
}

// ---------------------------------------------------------------------------
__global__ void final_kernel(const float* __restrict__ feats,
                             const float* __restrict__ dw,
                             float* __restrict__ out) {
    int b = threadIdx.x;
    if (b < B_) {
        float s = 0.f;
        for (int f = 0; f < 99; ++f) s += feats[b*99 + f] * dw[f];
        out[b] = s;
    }
}

extern "C" void kernel_launch(void* const* d_in, const int* in_sizes, int n_in,
                              void* d_out, int out_size, void* d_ws, size_t ws_size,
                              hipStream_t stream) {
    const int*   qtok = (const int*)d_in[0];
    const int*   dtok = (const int*)d_in[1];
    const float* emb  = (const float*)d_in[2];
    const float* w1   = (const float*)d_in[3];
    const float* w2   = (const float*)d_in[4];
    const float* w3   = (const float*)d_in[5];
    const float* b1   = (const float*)d_in[6];
    const float* b2   = (const float*)d_in[7];
    const float* b3   = (const float*)d_in[8];
    const float* dw   = (const float*)d_in[9];
    float* out = (float*)d_out;

    char* w = (char*)d_ws;
    u16*   Wt2   = (u16*)w;                      // 491,520 B
    u16*   Ag    = (u16*)(w + 491520);           // 32770*320*2 = 20,972,800
    u16*   qg    = (u16*)(w + 21464320);         // 3*128*32*128*2  = 3,145,728
    u16*   dgm   = (u16*)(w + 24610048);         // 3*128*208*128*2 = 20,447,232
    float* invq_ = (float*)(w + 45057280);       // 49,152
    float* invd_ = (float*)(w + 45106432);       // 319,488
    float* feats = (float*)(w + 45425920);       // 50,688 -> total 45,476,608

    prep_gather_kernel<<<dim3(24, B_), 256, 0, stream>>>(
        qtok, dtok, emb, w1, w2, w3, Ag, Wt2);

    const int conv_lds = 76064;                  // g1 worst case; 2 blocks/CU all grams
    hipFuncSetAttribute(reinterpret_cast<const void*>(conv_kernel),
                        hipFuncAttributeMaxDynamicSharedMemorySize, conv_lds);
    conv_kernel<<<dim3(2048), 256, conv_lds, stream>>>(
        Ag, Wt2, b1, b2, b3, qg, dgm, invq_, invd_);

    pool_kernel<<<dim3(3, B_), 256, 0, stream>>>(qg, dgm, invq_, invd_, qtok, dtok, feats);

    final_kernel<<<1, 128, 0, stream>>>(feats, dw, out);
}